// Round 1
// baseline (225.744 us; speedup 1.0000x reference)
//
#include <hip/hip_runtime.h>

typedef short bf16x8 __attribute__((ext_vector_type(8)));
typedef float f32x4 __attribute__((ext_vector_type(4)));
typedef unsigned short u16;

__device__ __forceinline__ u16 f2bf(float f) {
    unsigned u = __builtin_bit_cast(unsigned, f);
    return (u16)((u + 0x7fffu + ((u >> 16) & 1u)) >> 16);   // RNE
}

// ---------------- kernel 1: transpose + zero out + counter -------------------
// blocks [0,40):   ApT/AmT[k][o][d] = (Mp +/- Mm)[k][d][o]
// blocks [40,168): zero d_out (2 MiB); block 40 zeros the task counter
__global__ __launch_bounds__(256)
void k_pre(const float* __restrict__ Mp, const float* __restrict__ Mm,
           float* __restrict__ ApT, float* __restrict__ AmT,
           float* __restrict__ out, int* __restrict__ counter) {
    __shared__ float tp[64 * 65], tm[64 * 65];
    if (blockIdx.x < 40) {
        const int k = blockIdx.x, tid = threadIdx.x;
        for (int f = tid; f < 4096; f += 256) {          // f = d*64 + o
            int d = f >> 6, o = f & 63;
            float p = Mp[k * 4096 + f], m = Mm[k * 4096 + f];
            tp[o * 65 + d] = p + m;
            tm[o * 65 + d] = p - m;
        }
        __syncthreads();
        for (int f = tid; f < 4096; f += 256) {          // f = o*64 + d
            int o = f >> 6, d = f & 63;
            ApT[k * 4096 + f] = tp[o * 65 + d];
            AmT[k * 4096 + f] = tm[o * 65 + d];
        }
    } else {
        const int bz = blockIdx.x - 40;                  // 128 blocks x 4096 floats
        if (bz == 0 && threadIdx.x == 0) *counter = 0;
        float* po = out + bz * 4096;
        #pragma unroll
        for (int i = 0; i < 4; ++i)
            *(f32x4*)(po + (threadIdx.x + i * 256) * 4) = (f32x4){0.f, 0.f, 0.f, 0.f};
    }
}

// ---------------- kernel 2: xpad  ||  build W (B-fragment layout) ------------
// blocks [0,256):    xpad[b][r][d] bf16 (r<4096 zeros, 4096+t = x[b,t,:])
// blocks [256,2304): build Wtot: one s-PARITY per block (32 s each)
//   NEW: store each 8KB s-slice permuted into MFMA B-fragment order so
//   k_spectral can load B operands straight from global, coalesced:
//     slice offset = ((ks*4+nt)*64 + lane)*8 + e
//     where o = nt*16 + (lane&15), d = (ks*4 + (lane>>4))*8 + e
__global__ __launch_bounds__(256)
void k_mid(const float* __restrict__ x, u16* __restrict__ xpad,
           const float* __restrict__ phi, const float* __restrict__ ApT,
           const float* __restrict__ AmT, const float* __restrict__ Mar,
           u16* __restrict__ wg) {
    if (blockIdx.x < 256) {
        const int u = blockIdx.x;
        #pragma unroll
        for (int i = 0; i < 4; ++i) {
            int gid = (u * 4 + i) * 256 + threadIdx.x;
            int b = gid >> 17, rem = gid & 131071;
            int r = rem >> 4, c4 = rem & 15;
            u16 o0 = 0, o1 = 0, o2 = 0, o3 = 0;
            if (r >= 4096) {
                const f32x4 v = *(const f32x4*)(x + ((b << 12) + (r - 4096)) * 64 + c4 * 4);
                o0 = f2bf(v.x); o1 = f2bf(v.y); o2 = f2bf(v.z); o3 = f2bf(v.w);
            }
            u16* p = xpad + ((b << 13) + r) * 64 + c4 * 4;
            p[0] = o0; p[1] = o1; p[2] = o2; p[3] = o3;
        }
    } else {
        const int bi  = blockIdx.x - 256;
        const int par = bi & 1;                          // s parity
        const int sbq = bi >> 1;
        const int sb  = sbq >> 4, qb = sbq & 15;
        const int q   = qb * 256 + threadIdx.x;
        const int o   = q >> 6, d = q & 63;
        const float* A = (par ? AmT : ApT);

        // fragment-layout target index for this (o,d)
        const int nt_  = o >> 4, m15_ = o & 15;
        const int ks_  = d >> 5, q4_ = (d >> 3) & 3, e_ = d & 7;
        const int pidx = ((ks_ * 4 + nt_) * 64 + (q4_ * 16 + m15_)) * 8 + e_;

        float a[40];
        #pragma unroll
        for (int k = 0; k < 40; ++k) a[k] = A[k * 4096 + q];   // coalesced

        #pragma unroll 2
        for (int m = 0; m < 32; ++m) {
            const int s = sb * 64 + 2 * m + par;
            const float* ph = phi + s * 40;              // wave-uniform -> s_load
            float e0 = 0.f, e1 = 0.f;
            #pragma unroll
            for (int k = 0; k < 40; k += 2) { e0 += ph[k] * a[k]; e1 += ph[k + 1] * a[k + 1]; }
            float ev = e0 + e1;
            if (s < 3) ev += Mar[o * 192 + d * 3 + s];   // fold AR term
            wg[(size_t)s * 4096 + pidx] = f2bf(ev);
        }
    }
}

// ---------------- kernel 3: triangular conv-GEMM, barrier-free j-loop --------
// wave = (t-half, batch): each wave owns a 64t x 64o tile, loops over ALL s.
// B operands loaded global->reg (fragment-layout wg), double-buffered.
// x window stays in LDS (XOR-swizzled, 0-conflict). No per-j barriers,
// no parity merge. 3 barriers per unit total.
__global__ __launch_bounds__(256, 2)
void k_spectral(const u16* __restrict__ xpad, const u16* __restrict__ wg,
                float* __restrict__ out, int* __restrict__ counter) {
    __shared__ __align__(16) u16 xs[2 * 191 * 64];       // 47.75 KB x window
    __shared__ int sh;

    const int tid  = threadIdx.x;
    const int lane = tid & 63, w = tid >> 6;
    const int m15  = lane & 15, q4 = lane >> 4;
    const int th   = w >> 1, batch = w & 1;              // wave = (t-half, batch)

    for (;;) {
        __syncthreads();                                 // xs/sh reuse guard
        if (tid == 0) sh = atomicAdd(counter, 1);
        __syncthreads();
        const int U = sh;
        if (U >= 1120) break;

        // taper: U<992 -> full unit; else half task (32-s) of unit 992+(U-992)/2
        int mu = U, shalf = 0, slen = 64;
        if (U >= 992) { mu = 992 + ((U - 992) >> 1); shalf = (U - 992) & 1; slen = 32; }
        // J-major unit decode: group g=J>>1, G(g)=g(65-g), column cnt=32-g
        int g = 0;
        #pragma unroll 1
        while (g < 31 && (g + 1) * (64 - g) <= mu) ++g;
        const int rem = mu - g * (65 - g);
        const int cnt = 32 - g;
        const int col = (rem >= cnt) ? 1 : 0;
        const int J = 2 * g + col;
        const int I = g + (col ? rem - cnt : rem);
        const int t0 = I << 7, s0 = (J << 6) + (shalf << 5);
        const int nrows = 127 + slen;
        const int base = 4096 + t0 - s0 - (slen - 1);    // window start row in xpad

        // ---- stage x window: nrows rows/batch ----
        #pragma unroll
        for (int b = 0; b < 2; ++b) {
            #pragma unroll 1
            for (int f = tid; f < nrows * 8; f += 256) {
                int r = f >> 3, c = f & 7;
                bf16x8 v = *(const bf16x8*)(xpad + (size_t)((b << 13) + base + r) * 64 + c * 8);
                *(bf16x8*)(xs + ((b * 191 + r) * 8 + (c ^ (r & 7))) * 8) = v;
            }
        }
        __syncthreads();                                 // window visible

        f32x4 acc[4][4];
        #pragma unroll
        for (int mt = 0; mt < 4; ++mt)
            #pragma unroll
            for (int nt = 0; nt < 4; ++nt)
                acc[mt][nt] = (f32x4){0.f, 0.f, 0.f, 0.f};

        const u16* xb = xs + batch * (191 * 64);
        const int rb = th * 64 + (slen - 1) + m15;       // + mt*16 - ds

#define LOADW(BUF, S)                                                          \
        {                                                                      \
            const u16* wp_ = wg + (size_t)(S) * 4096 + lane * 8;               \
            _Pragma("unroll")                                                  \
            for (int f = 0; f < 8; ++f) BUF[f] = *(const bf16x8*)(wp_ + f * 512); \
        }

#define COMPUTE_S(BUF, DS)                                                     \
        {                                                                      \
            const int ds_ = (DS);                                              \
            _Pragma("unroll")                                                  \
            for (int ks = 0; ks < 2; ++ks) {                                   \
                const int kq = ks * 4 + q4;                                    \
                _Pragma("unroll")                                              \
                for (int mt = 0; mt < 4; ++mt) {                               \
                    int r = rb + mt * 16 - ds_;                                \
                    bf16x8 av = *(const bf16x8*)(xb + (r * 8 + (kq ^ (r & 7))) * 8); \
                    acc[mt][0] = __builtin_amdgcn_mfma_f32_16x16x32_bf16(av, BUF[ks * 4 + 0], acc[mt][0], 0, 0, 0); \
                    acc[mt][1] = __builtin_amdgcn_mfma_f32_16x16x32_bf16(av, BUF[ks * 4 + 1], acc[mt][1], 0, 0, 0); \
                    acc[mt][2] = __builtin_amdgcn_mfma_f32_16x16x32_bf16(av, BUF[ks * 4 + 2], acc[mt][2], 0, 0, 0); \
                    acc[mt][3] = __builtin_amdgcn_mfma_f32_16x16x32_bf16(av, BUF[ks * 4 + 3], acc[mt][3], 0, 0, 0); \
                }                                                              \
            }                                                                  \
        }

        bf16x8 b0[8], b1[8];
        LOADW(b0, s0);
        const int half = slen >> 1;
        #pragma unroll 1
        for (int jj = 0; jj < half; ++jj) {
            LOADW(b1, s0 + 2 * jj + 1);                  // odd slice
            COMPUTE_S(b0, 2 * jj);                       // even slice
            if (jj + 1 < half) LOADW(b0, s0 + 2 * jj + 2);
            COMPUTE_S(b1, 2 * jj + 1);
        }
#undef LOADW
#undef COMPUTE_S

        // ---- epilogue: every wave writes its own 64t x 64o tile ----
        #pragma unroll
        for (int mt = 0; mt < 4; ++mt) {
            int t = t0 + th * 64 + mt * 16 + q4 * 4;
            #pragma unroll
            for (int nt = 0; nt < 4; ++nt) {
                int o = nt * 16 + m15;
                float* op = out + (size_t)((batch << 12) + t) * 64 + o;
                #pragma unroll
                for (int r = 0; r < 4; ++r)
                    atomicAdd(op + r * 64, acc[mt][nt][r]);
            }
        }
    }
}

// ---------------------------------------------------------------------------
extern "C" void kernel_launch(void* const* d_in, const int* in_sizes, int n_in,
                              void* d_out, int out_size, void* d_ws, size_t ws_size,
                              hipStream_t stream) {
    const float* x   = (const float*)d_in[0];   // (2, 4096, 64)
    const float* phi = (const float*)d_in[1];   // (4096, 40)
    const float* M   = (const float*)d_in[2];   // (64, 64, 3)
    const float* Mp  = (const float*)d_in[3];   // (40, 64, 64)
    const float* Mm  = (const float*)d_in[4];   // (40, 64, 64)
    float* out = (float*)d_out;                 // (2, 4096, 64)

    // ws: [0,4096) counter | xpad 2 MiB | wg 32 MiB | ApT/AmT 2x640 KiB
    int* counter = (int*)d_ws;
    u16* xpad = (u16*)((char*)d_ws + 4096);
    u16* wg   = (u16*)((char*)d_ws + 4096 + 2097152);
    float* ApT = (float*)((char*)d_ws + 4096 + 2097152 + 33554432);
    float* AmT = ApT + 40 * 4096;

    k_pre<<<168, 256, 0, stream>>>(Mp, Mm, ApT, AmT, out, counter);
    k_mid<<<2304, 256, 0, stream>>>(x, xpad, phi, ApT, AmT, M, wg);
    k_spectral<<<512, 256, 0, stream>>>(xpad, wg, out, counter);
}

// Round 3
// 223.051 us; speedup vs baseline: 1.0121x; 1.0121x over previous
//
#include <hip/hip_runtime.h>

typedef short bf16x8 __attribute__((ext_vector_type(8)));
typedef float f32x4 __attribute__((ext_vector_type(4)));
typedef unsigned short u16;

__device__ __forceinline__ u16 f2bf(float f) {
    unsigned u = __builtin_bit_cast(unsigned, f);
    return (u16)((u + 0x7fffu + ((u >> 16) & 1u)) >> 16);   // RNE
}

// ---------------- kernel 1: transpose + zero out + counter -------------------
// blocks [0,40):   ApT/AmT[k][o][d] = (Mp +/- Mm)[k][d][o]
// blocks [40,168): zero d_out (2 MiB); block 40 zeros the task counter
__global__ __launch_bounds__(256)
void k_pre(const float* __restrict__ Mp, const float* __restrict__ Mm,
           float* __restrict__ ApT, float* __restrict__ AmT,
           float* __restrict__ out, int* __restrict__ counter) {
    __shared__ float tp[64 * 65], tm[64 * 65];
    if (blockIdx.x < 40) {
        const int k = blockIdx.x, tid = threadIdx.x;
        for (int f = tid; f < 4096; f += 256) {          // f = d*64 + o
            int d = f >> 6, o = f & 63;
            float p = Mp[k * 4096 + f], m = Mm[k * 4096 + f];
            tp[o * 65 + d] = p + m;
            tm[o * 65 + d] = p - m;
        }
        __syncthreads();
        for (int f = tid; f < 4096; f += 256) {          // f = o*64 + d
            int o = f >> 6, d = f & 63;
            ApT[k * 4096 + f] = tp[o * 65 + d];
            AmT[k * 4096 + f] = tm[o * 65 + d];
        }
    } else {
        const int bz = blockIdx.x - 40;                  // 128 blocks x 4096 floats
        if (bz == 0 && threadIdx.x == 0) *counter = 0;
        float* po = out + bz * 4096;
        #pragma unroll
        for (int i = 0; i < 4; ++i)
            *(f32x4*)(po + (threadIdx.x + i * 256) * 4) = (f32x4){0.f, 0.f, 0.f, 0.f};
    }
}

// ---------------- kernel 2: xpad  ||  build W (B-fragment layout) ------------
// blocks [0,256):    xpad[b][r][d] bf16 (r<4096 zeros, 4096+t = x[b,t,:])
// blocks [256,2304): build Wtot: one s-PARITY per block (32 s each)
//   store each 8KB s-slice permuted into MFMA B-fragment order so k_spectral
//   loads B operands straight from global, coalesced:
//     slice offset = ((ks*4+nt)*64 + lane)*8 + e
//     where o = nt*16 + (lane&15), d = (ks*4 + (lane>>4))*8 + e
__global__ __launch_bounds__(256)
void k_mid(const float* __restrict__ x, u16* __restrict__ xpad,
           const float* __restrict__ phi, const float* __restrict__ ApT,
           const float* __restrict__ AmT, const float* __restrict__ Mar,
           u16* __restrict__ wg) {
    if (blockIdx.x < 256) {
        const int u = blockIdx.x;
        #pragma unroll
        for (int i = 0; i < 4; ++i) {
            int gid = (u * 4 + i) * 256 + threadIdx.x;
            int b = gid >> 17, rem = gid & 131071;
            int r = rem >> 4, c4 = rem & 15;
            u16 o0 = 0, o1 = 0, o2 = 0, o3 = 0;
            if (r >= 4096) {
                const f32x4 v = *(const f32x4*)(x + ((b << 12) + (r - 4096)) * 64 + c4 * 4);
                o0 = f2bf(v.x); o1 = f2bf(v.y); o2 = f2bf(v.z); o3 = f2bf(v.w);
            }
            u16* p = xpad + ((b << 13) + r) * 64 + c4 * 4;
            p[0] = o0; p[1] = o1; p[2] = o2; p[3] = o3;
        }
    } else {
        const int bi  = blockIdx.x - 256;
        const int par = bi & 1;                          // s parity
        const int sbq = bi >> 1;
        const int sb  = sbq >> 4, qb = sbq & 15;
        const int q   = qb * 256 + threadIdx.x;
        const int o   = q >> 6, d = q & 63;
        const float* A = (par ? AmT : ApT);

        // fragment-layout target index for this (o,d)
        const int nt_  = o >> 4, m15_ = o & 15;
        const int ks_  = d >> 5, q4_ = (d >> 3) & 3, e_ = d & 7;
        const int pidx = ((ks_ * 4 + nt_) * 64 + (q4_ * 16 + m15_)) * 8 + e_;

        float a[40];
        #pragma unroll
        for (int k = 0; k < 40; ++k) a[k] = A[k * 4096 + q];   // coalesced

        #pragma unroll 2
        for (int m = 0; m < 32; ++m) {
            const int s = sb * 64 + 2 * m + par;
            const float* ph = phi + s * 40;              // wave-uniform -> s_load
            float e0 = 0.f, e1 = 0.f;
            #pragma unroll
            for (int k = 0; k < 40; k += 2) { e0 += ph[k] * a[k]; e1 += ph[k + 1] * a[k + 1]; }
            float ev = e0 + e1;
            if (s < 3) ev += Mar[o * 192 + d * 3 + s];   // fold AR term
            wg[(size_t)s * 4096 + pidx] = f2bf(ev);
        }
    }
}

// ---------------- kernel 3: triangular conv-GEMM, depth-2 W prefetch ---------
// wave = (t-half, batch): each wave owns a 64t x 64o tile, loops over ALL s.
// B operands loaded global->reg (fragment-layout wg), FOUR buffers, prefetch
// distance 2 slice-pairs: loads issued at pair p are consumed at pair p+2
// (~64 MFMAs of cover vs ~1 phase before -> hides 400-600cy L2 latency).
// x window in LDS (XOR-swizzled, 0-conflict). setprio(1) around MFMA clusters.
__global__ __launch_bounds__(256, 2)
void k_spectral(const u16* __restrict__ xpad, const u16* __restrict__ wg,
                float* __restrict__ out, int* __restrict__ counter) {
    __shared__ __align__(16) u16 xs[2 * 191 * 64];       // 47.75 KB x window
    __shared__ int sh;

    const int tid  = threadIdx.x;
    const int lane = tid & 63, w = tid >> 6;
    const int m15  = lane & 15, q4 = lane >> 4;
    const int th   = w >> 1, batch = w & 1;              // wave = (t-half, batch)

    for (;;) {
        __syncthreads();                                 // xs/sh reuse guard
        if (tid == 0) sh = atomicAdd(counter, 1);
        __syncthreads();
        const int U = sh;
        if (U >= 1120) break;

        // taper: U<992 -> full unit; else half task (32-s) of unit 992+(U-992)/2
        int mu = U, shalf = 0, slen = 64;
        if (U >= 992) { mu = 992 + ((U - 992) >> 1); shalf = (U - 992) & 1; slen = 32; }
        // J-major unit decode: group g=J>>1, G(g)=g(65-g), column cnt=32-g
        int g = 0;
        #pragma unroll 1
        while (g < 31 && (g + 1) * (64 - g) <= mu) ++g;
        const int rem = mu - g * (65 - g);
        const int cnt = 32 - g;
        const int col = (rem >= cnt) ? 1 : 0;
        const int J = 2 * g + col;
        const int I = g + (col ? rem - cnt : rem);
        const int t0 = I << 7, s0 = (J << 6) + (shalf << 5);
        const int nrows = 127 + slen;
        const int base = 4096 + t0 - s0 - (slen - 1);    // window start row in xpad

        // ---- stage x window: nrows rows/batch ----
        #pragma unroll
        for (int b = 0; b < 2; ++b) {
            #pragma unroll 1
            for (int f = tid; f < nrows * 8; f += 256) {
                int r = f >> 3, c = f & 7;
                bf16x8 v = *(const bf16x8*)(xpad + (size_t)((b << 13) + base + r) * 64 + c * 8);
                *(bf16x8*)(xs + ((b * 191 + r) * 8 + (c ^ (r & 7))) * 8) = v;
            }
        }
        __syncthreads();                                 // window visible

        f32x4 acc[4][4];
        #pragma unroll
        for (int mt = 0; mt < 4; ++mt)
            #pragma unroll
            for (int nt = 0; nt < 4; ++nt)
                acc[mt][nt] = (f32x4){0.f, 0.f, 0.f, 0.f};

        const u16* xb = xs + batch * (191 * 64);
        const int rb = th * 64 + (slen - 1) + m15;       // + mt*16 - ds

#define LOADW(BUF, S)                                                          \
        {                                                                      \
            const u16* wp_ = wg + (size_t)(S) * 4096 + lane * 8;               \
            _Pragma("unroll")                                                  \
            for (int f = 0; f < 8; ++f) BUF[f] = *(const bf16x8*)(wp_ + f * 512); \
        }

#define COMPUTE_S(BUF, DS)                                                     \
        {                                                                      \
            const int ds_ = (DS);                                              \
            _Pragma("unroll")                                                  \
            for (int ks = 0; ks < 2; ++ks) {                                   \
                const int kq = ks * 4 + q4;                                    \
                _Pragma("unroll")                                              \
                for (int mt = 0; mt < 4; ++mt) {                               \
                    int r = rb + mt * 16 - ds_;                                \
                    bf16x8 av = *(const bf16x8*)(xb + (r * 8 + (kq ^ (r & 7))) * 8); \
                    acc[mt][0] = __builtin_amdgcn_mfma_f32_16x16x32_bf16(av, BUF[ks * 4 + 0], acc[mt][0], 0, 0, 0); \
                    acc[mt][1] = __builtin_amdgcn_mfma_f32_16x16x32_bf16(av, BUF[ks * 4 + 1], acc[mt][1], 0, 0, 0); \
                    acc[mt][2] = __builtin_amdgcn_mfma_f32_16x16x32_bf16(av, BUF[ks * 4 + 2], acc[mt][2], 0, 0, 0); \
                    acc[mt][3] = __builtin_amdgcn_mfma_f32_16x16x32_bf16(av, BUF[ks * 4 + 3], acc[mt][3], 0, 0, 0); \
                }                                                              \
            }                                                                  \
        }

        bf16x8 b0[8], b1[8], b2[8], b3[8];
        const int half = slen >> 1;                      // 16 or 32 (even)
        LOADW(b0, s0);     LOADW(b1, s0 + 1);
        LOADW(b2, s0 + 2); LOADW(b3, s0 + 3);
        #pragma unroll 1
        for (int j2 = 0; j2 < half; j2 += 2) {
            __builtin_amdgcn_s_setprio(1);
            COMPUTE_S(b0, 2 * j2);
            COMPUTE_S(b1, 2 * j2 + 1);
            __builtin_amdgcn_s_setprio(0);
            if (j2 + 2 < half) { LOADW(b0, s0 + 2 * j2 + 4); LOADW(b1, s0 + 2 * j2 + 5); }
            __builtin_amdgcn_s_setprio(1);
            COMPUTE_S(b2, 2 * j2 + 2);
            COMPUTE_S(b3, 2 * j2 + 3);
            __builtin_amdgcn_s_setprio(0);
            if (j2 + 2 < half) { LOADW(b2, s0 + 2 * j2 + 6); LOADW(b3, s0 + 2 * j2 + 7); }
        }
#undef LOADW
#undef COMPUTE_S

        // ---- epilogue: every wave writes its own 64t x 64o tile ----
        #pragma unroll
        for (int mt = 0; mt < 4; ++mt) {
            int t = t0 + th * 64 + mt * 16 + q4 * 4;
            #pragma unroll
            for (int nt = 0; nt < 4; ++nt) {
                int o = nt * 16 + m15;
                float* op = out + (size_t)((batch << 12) + t) * 64 + o;
                #pragma unroll
                for (int r = 0; r < 4; ++r)
                    atomicAdd(op + r * 64, acc[mt][nt][r]);
            }
        }
    }
}

// ---------------------------------------------------------------------------
extern "C" void kernel_launch(void* const* d_in, const int* in_sizes, int n_in,
                              void* d_out, int out_size, void* d_ws, size_t ws_size,
                              hipStream_t stream) {
    const float* x   = (const float*)d_in[0];   // (2, 4096, 64)
    const float* phi = (const float*)d_in[1];   // (4096, 40)
    const float* M   = (const float*)d_in[2];   // (64, 64, 3)
    const float* Mp  = (const float*)d_in[3];   // (40, 64, 64)
    const float* Mm  = (const float*)d_in[4];   // (40, 64, 64)
    float* out = (float*)d_out;                 // (2, 4096, 64)

    // ws: [0,4096) counter | xpad 2 MiB | wg 32 MiB | ApT/AmT 2x640 KiB
    int* counter = (int*)d_ws;
    u16* xpad = (u16*)((char*)d_ws + 4096);
    u16* wg   = (u16*)((char*)d_ws + 4096 + 2097152);
    float* ApT = (float*)((char*)d_ws + 4096 + 2097152 + 33554432);
    float* AmT = ApT + 40 * 4096;

    k_pre<<<168, 256, 0, stream>>>(Mp, Mm, ApT, AmT, out, counter);
    k_mid<<<2304, 256, 0, stream>>>(x, xpad, phi, ApT, AmT, M, wg);
    k_spectral<<<512, 256, 0, stream>>>(xpad, wg, out, counter);
}